// Round 9
// baseline (182.988 us; speedup 1.0000x reference)
//
#include <hip/hip_runtime.h>

// HarmonicFullyConnectedTensorProduct, lmax=2, MUL=64, B=1024, 11 paths.
// out[z,w,k] += sum_{u,v,m,n} x1[z,u,m] x2[z,v,n] W[p,w,u,v] C_p[m,n,k]
//
// Round 9 = round 8 (validated) + occupancy/TLP tuning:
//  - LDS trimmed to <=32768 B per block (smaller UC -> smaller sc1 slab,
//    rebuilt more often; total build work unchanged) -> 5 blocks/CU.
//  - reduce_out split by l3 group -> 768 blocks (3x TLP), disjoint k-slots.
// Core (unchanged): per u: A-frags from L2, T-form(u+1)->sT[next], MFMA(u)
// from sT[cur], ONE barrier; plain partial stores + reduce (no atomics).

#define NTHREADS 256
#define SMEM_BYTES 32768

typedef __attribute__((ext_vector_type(4))) float f32x4;
typedef __attribute__((ext_vector_type(8))) short s16x8;

__device__ __forceinline__ unsigned short f2bf(float x) {
    union { float f; unsigned u; } v; v.f = x;
    unsigned r = v.u + 0x7fffu + ((v.u >> 16) & 1u);   // RNE
    return (unsigned short)(r >> 16);
}

// ---------------- prep: W fp32 [p][w][u][v] -> bf16 [p][u][w][v] ----------------

__global__ __launch_bounds__(NTHREADS) void prep_w(const float* __restrict__ W,
                                                   unsigned short* __restrict__ Wb)
{
    int id = blockIdx.x * NTHREADS + threadIdx.x;   // (p,u,w,v4): 11*64*64*16
    int v4 = (id & 15) << 2;
    int w  = (id >> 4) & 63;
    int u  = (id >> 10) & 63;
    int p  = id >> 16;
    float4 f = *(const float4*)(W + (((size_t)p * 64 + w) * 64 + u) * 64 + v4);
    ushort4 h;
    h.x = f2bf(f.x); h.y = f2bf(f.y); h.z = f2bf(f.z); h.w = f2bf(f.w);
    *(ushort4*)(Wb + (((size_t)p * 64 + u) * 64 + w) * 64 + v4) = h;
}

// ---------------- main ----------------

struct KArgs {
    const float*          x1[3];
    const float*          x2[3];
    const unsigned short* Wb;
    const float*          C[11];
    float*                part[11];   // per-path partials [4 usub][1024][64][K1]
};

template <int M1, int N1, int K1, int ZT, int S1, int UC>
__device__ __forceinline__ void run_path(const float* __restrict__ x1g,
                                         const float* __restrict__ x2g,
                                         const unsigned short* __restrict__ Wbp,
                                         const float* __restrict__ Cg,
                                         float* __restrict__ partp,
                                         int local, char* __restrict__ smem)
{
    constexpr int KN   = K1 * N1;
    constexpr int NC   = ZT * K1 / 16;        // MFMA col-tiles
    constexpr bool EVEN = (NC % 2 == 0);
    constexpr int ROWT = EVEN ? 2 : 1;        // w-tiles per wave
    constexpr int COLT = EVEN ? NC / 2 : NC;  // col-tiles per wave
    constexpr int NI   = ZT / 4;              // T-form z-iters
    constexpr int SST  = UC * S1 + 4;         // sc1 z-stride (floats)
    constexpr int TROWS = ZT * K1;
    static_assert(512 + ZT * SST * 4 + 2 * TROWS * 72 * 2 <= SMEM_BYTES, "LDS");

    float*          sC  = (float*)smem;                        // [<=125]
    float*          sc1 = (float*)(smem + 512);                // [ZT][SST]
    unsigned short* sT0 = (unsigned short*)(smem + 512 + ZT * SST * 4);
    // sT0: 2 buffers x TROWS x 72 bf16

    const int t = threadIdx.x, lane = t & 63, wave = t >> 6;
    const int ln = lane & 15, q = lane >> 4;
    const int ztile = local >> 2, usub = local & 3;
    const int z0 = ztile * ZT, u0 = usub * 16;

    for (int i = t; i < M1 * N1 * K1; i += NTHREADS) sC[i] = Cg[i];
    __syncthreads();

    // cooperative c1 slab build: sc1[z][uu2*S1 + k*N1+n] for u in [u0+us0, +UC)
    auto build_slab = [&](int us0) {
        for (int i = t; i < ZT * UC * KN; i += NTHREADS) {
            int z   = i / (UC * KN);
            int r   = i - z * (UC * KN);
            int uu2 = r / KN;
            int j   = r - uu2 * KN;
            int k   = j / N1, n = j - k * N1;
            const float* x1r = x1g + ((size_t)(z0 + z) * 64 + u0 + us0 + uu2) * M1;
            float s = 0.f;
#pragma unroll
            for (int m = 0; m < M1; ++m) s += x1r[m] * sC[(m * N1 + n) * K1 + k];
            sc1[z * SST + uu2 * S1 + j] = s;
        }
    };

    // x2 for this thread's (z = i*4+wave, v = lane), reused across all u
    float xr[NI][N1];
#pragma unroll
    for (int i = 0; i < NI; ++i) {
        const float* xp = x2g + ((size_t)(z0 + i * 4 + wave) * 64 + lane) * N1;
#pragma unroll
        for (int n = 0; n < N1; ++n) xr[i][n] = xp[n];
    }

    // T-form for u-offset uf into buffer sTn
    auto tform = [&](int uf, unsigned short* sTn) {
        const int uus = uf % UC;
#pragma unroll
        for (int i = 0; i < NI; ++i) {
            const int z = i * 4 + wave;                 // wave-uniform
            const float4* cp = (const float4*)&sc1[z * SST + uus * S1];
            float c1v[S1];
#pragma unroll
            for (int jj = 0; jj < S1 / 4; ++jj) {
                float4 f = cp[jj];
                c1v[jj * 4 + 0] = f.x; c1v[jj * 4 + 1] = f.y;
                c1v[jj * 4 + 2] = f.z; c1v[jj * 4 + 3] = f.w;
            }
#pragma unroll
            for (int k = 0; k < K1; ++k) {
                float s = 0.f;
#pragma unroll
                for (int n = 0; n < N1; ++n) s += xr[i][n] * c1v[k * N1 + n];
                sTn[(z * K1 + k) * 72 + lane] = f2bf(s);
            }
        }
    };

    f32x4 acc[ROWT][COLT];
#pragma unroll
    for (int rt = 0; rt < ROWT; ++rt)
#pragma unroll
        for (int ci = 0; ci < COLT; ++ci) acc[rt][ci] = (f32x4){0.f, 0.f, 0.f, 0.f};

    build_slab(0);
    __syncthreads();
    tform(0, sT0);
    __syncthreads();

#pragma unroll 2
    for (int uu = 0; uu < 16; ++uu) {
        if (((uu + 1) % UC) == 0 && (uu + 1) < 16) {
            // refill sc1 for next slab; prior readers finished before last barrier
            build_slab(uu + 1);
            __syncthreads();
        }
        const int cur = uu & 1;
        unsigned short* sTc = sT0 + cur * (TROWS * 72);
        unsigned short* sTn = sT0 + (cur ^ 1) * (TROWS * 72);

        // A-frags for THIS u straight from L2 (issued early = in-iter prefetch)
        const unsigned short* wsrc = Wbp + (size_t)(u0 + uu) * 4096;
        s16x8 areg[ROWT][2];
#pragma unroll
        for (int rt = 0; rt < ROWT; ++rt) {
            const int wt = EVEN ? ((wave >> 1) * 2 + rt) : wave;
#pragma unroll
            for (int s2 = 0; s2 < 2; ++s2)
                areg[rt][s2] = *(const s16x8*)(wsrc + (wt * 16 + ln) * 64 + s2 * 32 + q * 8);
        }

        // T-form next u (writes sTn) — overlaps with MFMA below in the pipes
        if (uu < 15) tform(uu + 1, sTn);

        // MFMA from sTc
#pragma unroll
        for (int ci = 0; ci < COLT; ++ci) {
            const int c = EVEN ? ((wave & 1) * COLT + ci) : ci;
            s16x8 bf0 = *(const s16x8*)&sTc[(c * 16 + ln) * 72 + q * 8];
            s16x8 bf1 = *(const s16x8*)&sTc[(c * 16 + ln) * 72 + 32 + q * 8];
#pragma unroll
            for (int rt = 0; rt < ROWT; ++rt) {
                acc[rt][ci] = __builtin_amdgcn_mfma_f32_16x16x32_bf16(
                    areg[rt][0], bf0, acc[rt][ci], 0, 0, 0);
                acc[rt][ci] = __builtin_amdgcn_mfma_f32_16x16x32_bf16(
                    areg[rt][1], bf1, acc[rt][ci], 0, 0, 0);
            }
        }
        __syncthreads();
    }

    // ---- epilogue: plain stores to per-(path,usub) partials (no atomics)
#pragma unroll
    for (int rt = 0; rt < ROWT; ++rt) {
        const int wt = EVEN ? ((wave >> 1) * 2 + rt) : wave;
#pragma unroll
        for (int ci = 0; ci < COLT; ++ci) {
            const int c = EVEN ? ((wave & 1) * COLT + ci) : ci;
            const int col = c * 16 + ln;
            const int z = col / K1, k = col - z * K1;
            float* op = partp + ((size_t)(usub * 1024 + z0 + z) * 64) * K1 + k;
#pragma unroll
            for (int r = 0; r < 4; ++r)
                op[(wt * 16 + q * 4 + r) * K1] = acc[rt][ci][r];
        }
    }
}

__global__ __launch_bounds__(NTHREADS, 5) void tp_main(KArgs a)
{
    __shared__ __align__(16) char smem[SMEM_BYTES];

    const int bid = blockIdx.x;
    // heavy-first: p2,p10,p5,p7,p6 (256 ea, ZT16), then p1,p8,p3,p9,p4,p0 (128 ea, ZT32)
    const int starts[12] = {0, 256, 512, 768, 1024, 1280, 1408, 1536, 1664, 1792, 1920, 2048};
    int idx = 0;
#pragma unroll
    for (int i = 1; i < 12; ++i) idx += (bid >= starts[i]) ? 1 : 0;
    const int local = bid - starts[idx];

    switch (idx) {            //  M1 N1 K1 ZT S1 UC       (LDS: <=32768 each)
        case 0:  run_path<1,5,5,16,28, 4>(a.x1[0], a.x2[2], a.Wb + (size_t) 2*262144, a.C[2],  a.part[2],  local, smem); break;
        case 1:  run_path<5,5,5,16,28, 4>(a.x1[2], a.x2[2], a.Wb + (size_t)10*262144, a.C[10], a.part[10], local, smem); break;
        case 2:  run_path<3,3,5,16,16, 8>(a.x1[1], a.x2[1], a.Wb + (size_t) 5*262144, a.C[5],  a.part[5],  local, smem); break;
        case 3:  run_path<5,1,5,16, 8,16>(a.x1[2], a.x2[0], a.Wb + (size_t) 7*262144, a.C[7],  a.part[7],  local, smem); break;
        case 4:  run_path<3,5,3,16,16, 8>(a.x1[1], a.x2[2], a.Wb + (size_t) 6*262144, a.C[6],  a.part[6],  local, smem); break;
        case 5:  run_path<1,3,3,32,12, 2>(a.x1[0], a.x2[1], a.Wb + (size_t) 1*262144, a.C[1],  a.part[1],  local, smem); break;
        case 6:  run_path<5,3,3,32,12, 2>(a.x1[2], a.x2[1], a.Wb + (size_t) 8*262144, a.C[8],  a.part[8],  local, smem); break;
        case 7:  run_path<3,1,3,32, 4, 8>(a.x1[1], a.x2[0], a.Wb + (size_t) 3*262144, a.C[3],  a.part[3],  local, smem); break;
        case 8:  run_path<5,5,1,32, 8,16>(a.x1[2], a.x2[2], a.Wb + (size_t) 9*262144, a.C[9],  a.part[9],  local, smem); break;
        case 9:  run_path<3,3,1,32, 4,16>(a.x1[1], a.x2[1], a.Wb + (size_t) 4*262144, a.C[4],  a.part[4],  local, smem); break;
        case 10: run_path<1,1,1,32, 4,16>(a.x1[0], a.x2[0], a.Wb + (size_t) 0*262144, a.C[0],  a.part[0],  local, smem); break;
        default: break;
    }
}

// ---------------- reduce: sum partials into out[z][w][9], split by l3 ----------------

struct RArgs {
    const float* part[11];
    float*       out;
};

__global__ __launch_bounds__(NTHREADS) void reduce_out(RArgs r)
{
    const int g   = blockIdx.x >> 8;                            // 0:l0 1:l1 2:l2
    const int tid = (blockIdx.x & 255) * NTHREADS + threadIdx.x; // 65536 = z*64+w
    float* op = r.out + (size_t)tid * 9;

    if (g == 0) {            // k slot 0, paths {0,4,9}, K1=1
        const int P[3] = {0, 4, 9};
        float o = 0.f;
#pragma unroll
        for (int pi = 0; pi < 3; ++pi) {
            const float* pp = r.part[P[pi]];
#pragma unroll
            for (int us = 0; us < 4; ++us)
                o += pp[(size_t)(us * 65536) + tid];
        }
        op[0] = o;
    } else if (g == 1) {     // slots 1..3, paths {1,3,6,8}, K1=3
        const int P[4] = {1, 3, 6, 8};
        float o[3] = {0.f, 0.f, 0.f};
#pragma unroll
        for (int pi = 0; pi < 4; ++pi) {
            const float* pp = r.part[P[pi]];
#pragma unroll
            for (int us = 0; us < 4; ++us) {
                const float* row = pp + ((size_t)(us * 65536) + tid) * 3;
#pragma unroll
                for (int k = 0; k < 3; ++k) o[k] += row[k];
            }
        }
#pragma unroll
        for (int k = 0; k < 3; ++k) op[1 + k] = o[k];
    } else {                 // slots 4..8, paths {2,5,7,10}, K1=5
        const int P[4] = {2, 5, 7, 10};
        float o[5] = {0.f, 0.f, 0.f, 0.f, 0.f};
#pragma unroll
        for (int pi = 0; pi < 4; ++pi) {
            const float* pp = r.part[P[pi]];
#pragma unroll
            for (int us = 0; us < 4; ++us) {
                const float* row = pp + ((size_t)(us * 65536) + tid) * 5;
#pragma unroll
                for (int k = 0; k < 5; ++k) o[k] += row[k];
            }
        }
#pragma unroll
        for (int k = 0; k < 5; ++k) op[4 + k] = o[k];
    }
}

// ---------------- launch ----------------

extern "C" void kernel_launch(void* const* d_in, const int* in_sizes, int n_in,
                              void* d_out, int out_size, void* d_ws, size_t ws_size,
                              hipStream_t stream)
{
    static const int cumK1[11] = {0, 1, 4, 9, 12, 13, 18, 21, 26, 29, 30}; // prefix of K1

    unsigned short* Wb = (unsigned short*)d_ws;                       // 5.77 MB
    float* partbase = (float*)((char*)d_ws + (6u << 20));             // 36.7 MB

    KArgs a;
    // dict order: x1_l0, x2_l0, x1_l1, x2_l1, x1_l2, x2_l2, W, C_0..C_10
    a.x1[0] = (const float*)d_in[0];
    a.x2[0] = (const float*)d_in[1];
    a.x1[1] = (const float*)d_in[2];
    a.x2[1] = (const float*)d_in[3];
    a.x1[2] = (const float*)d_in[4];
    a.x2[2] = (const float*)d_in[5];
    a.Wb = Wb;
    RArgs rr;
    for (int p = 0; p < 11; ++p) {
        a.C[p]    = (const float*)d_in[7 + p];
        a.part[p] = partbase + (size_t)cumK1[p] * 262144;   // 4*1024*64 per K1-slot
        rr.part[p] = a.part[p];
    }
    rr.out = (float*)d_out;

    prep_w<<<dim3(720896 / NTHREADS), NTHREADS, 0, stream>>>((const float*)d_in[6], Wb);
    tp_main<<<dim3(2048), NTHREADS, 0, stream>>>(a);
    reduce_out<<<dim3(768), NTHREADS, 0, stream>>>(rr);
}